// Round 8
// baseline (96.945 us; speedup 1.0000x reference)
//
#include <hip/hip_runtime.h>
#include <hip/hip_bf16.h>

// Chamfer loss: pred [8,4096,3] f32, gt [8,4096,3] f32 -> scalar f32.
// loss = mean_b[ mean(d1)+mean(d2) + 3*(mean(top2048(d1)) + mean(top2048(d2))) ]
//
// Round-8: R7 failed only because the qn __shfl sat inside `if (col==0)` —
// ds_bpermute from inactive source lanes is undefined. Shuffles are now
// wave-wide; only the atomicMin is guarded. Structure unchanged from R7:
// no LDS staging, no __syncthreads; B streamed from L2 (packed once by a
// pre-pass). MFMA zero-trick: A rows k>=4 are zero, so B k>=4 values are
// don't-cares (finite) -> all 64 lanes load the same 32 B-columns, half-1
// lanes' loads are harmless duplicates. 2-way g-split + atomicMin epilogue
// gives 16 waves/CU at the 128-VGPR occupancy cap.

#define BATCH 8
#define NPTS  4096
#define TOPK  2048
#define BT    256
#define NROW  (2 * BATCH)      // 16 rows = b*2+dir
#define GSPLIT 2
#define GHALF (NPTS / GSPLIT)  // 2048 db points per split
#define NTILE (GHALF / 32)     // 64 tiles of 32 per wave

typedef _Float16 half8 __attribute__((ext_vector_type(8)));
typedef float floatx16 __attribute__((ext_vector_type(16)));

static __device__ inline unsigned pack_h2(float a, float b) {
  unsigned short ua = __builtin_bit_cast(unsigned short, (_Float16)a);
  unsigned short ub = __builtin_bit_cast(unsigned short, (_Float16)b);
  return (unsigned)ua | ((unsigned)ub << 16);
}

// ---------------- Kernel P: pack db rows + sentinel-init minsq + zero out --
// 16 blocks x 256 thr. gpack[row][i] = f16x4(-2x,-2y,-2z,|g|^2) of row's db.
__global__ __launch_bounds__(BT) void pack_kernel(
    const float* __restrict__ pred, const float* __restrict__ gt,
    uint2* __restrict__ gpack, unsigned* __restrict__ minsq,
    float* __restrict__ out) {
  const int row = blockIdx.x;          // b*2 + dir
  const int b   = row >> 1;
  const int dir = row & 1;
  const float* g = (dir == 0 ? gt : pred) + (size_t)b * NPTS * 3;
  const int tid = threadIdx.x;

#pragma unroll
  for (int s = 0; s < NPTS / BT; s++) {
    int gi = tid + BT * s;
    float x = g[3 * gi + 0];
    float y = g[3 * gi + 1];
    float z = g[3 * gi + 2];
    float gn = x * x + y * y + z * z;
    gpack[(size_t)row * NPTS + gi] =
        make_uint2(pack_h2(-2.0f * x, -2.0f * y), pack_h2(-2.0f * z, gn));
    minsq[(size_t)row * NPTS + gi] = 0x7F7F7F7Fu;   // ~3.39e38 sentinel
  }
  if (row == 0 && tid == 0) out[0] = 0.0f;
}

// ---------------- Kernel A: min squared distance via 32x32 MFMA, streaming -
// grid (32, GSPLIT, 16) = 1024 blocks -> 4 blocks/CU, 16 waves/CU (VGPR cap).
// Each wave: 32 queries x 2048 g, straight from L2, running min in 16 C-regs.
__global__ __launch_bounds__(BT, 4) void nn_min_kernel(
    const float* __restrict__ pred, const float* __restrict__ gt,
    const uint2* __restrict__ gpack, unsigned* __restrict__ minsq) {
  const int qb  = blockIdx.x;          // 0..31: query block of 128
  const int gs  = blockIdx.y;          // 0..1: g-split
  const int row = blockIdx.z;          // b*2 + dir
  const int b   = row >> 1;
  const int dir = row & 1;
  const float* q = (dir == 0 ? pred : gt) + (size_t)b * NPTS * 3;

  const int tid  = threadIdx.x;
  const int lane = tid & 63;
  const int wave = tid >> 6;
  const int col  = lane & 31;
  const int half = lane >> 5;
  const int q0w  = qb * 128 + wave * 32;   // this wave's 32 queries

  // exact fp32 qn, valid in every lane (half1 duplicates half0's query)
  float qx = q[3 * (q0w + col) + 0];
  float qy = q[3 * (q0w + col) + 1];
  float qz = q[3 * (q0w + col) + 2];
  float qn = qx * qx + qy * qy + qz * qz;

  // A fragment: lanes<32 hold A[m=col][k=0..7]=(qx,qy,qz,1,0...); lanes>=32
  // hold k=8..15 rows: zero. => B values at k>=4 are don't-cares (finite).
  half8 afrag = {};
  if (half == 0) {
    afrag[0] = (_Float16)qx;
    afrag[1] = (_Float16)qy;
    afrag[2] = (_Float16)qz;
    afrag[3] = (_Float16)1.0f;
  }

  const uint2* gp = gpack + (size_t)row * NPTS + gs * GHALF;

  floatx16 macc;
#pragma unroll
  for (int r = 0; r < 16; r++) macc[r] = 3.0e38f;
  const floatx16 czero = {};

#pragma unroll 2
  for (int t = 0; t < NTILE; t += 2) {
    // all lanes load; half1 lanes duplicate half0's columns (harmless: those
    // feed B rows k=8..15, which multiply A's zero rows)
    uint2 w0 = gp[t * 32 + col];
    uint2 w1 = gp[(t + 1) * 32 + col];
    union { int4 i; half8 h; } b0, b1;
    b0.i = make_int4((int)w0.x, (int)w0.y, 0, 0);
    b1.i = make_int4((int)w1.x, (int)w1.y, 0, 0);
    floatx16 r0 = __builtin_amdgcn_mfma_f32_32x32x16_f16(afrag, b0.h, czero, 0, 0, 0);
    floatx16 r1 = __builtin_amdgcn_mfma_f32_32x32x16_f16(afrag, b1.h, czero, 0, 0, 0);
#pragma unroll
    for (int r = 0; r < 16; r++)
      macc[r] = fminf(macc[r], fminf(r0[r], r1[r]));   // v_min3 fold
  }

  // Min across the 32 g-columns (xor <=16 stays within each 32-lane half).
#pragma unroll
  for (int mask = 1; mask < 32; mask <<= 1) {
#pragma unroll
    for (int r = 0; r < 16; r++)
      macc[r] = fminf(macc[r], __shfl_xor(macc[r], mask));
  }

  // C/D rows: row = (reg&3) + 8*(reg>>2) + 4*half [m74/m101-verified].
  // Attach exact fp32 qn (shuffled WAVE-WIDE — R7's bug was shuffling under
  // divergent exec), clamp, combine across g-splits via atomicMin on
  // float-bits (nonneg => uint order == float order).
  unsigned* dst = minsq + (size_t)row * NPTS + q0w;
#pragma unroll
  for (int rg = 0; rg < 4; rg++) {
#pragma unroll
    for (int e = 0; e < 4; e++) {
      int r = 8 * rg + 4 * half + e;
      float qn_s = __shfl(qn, r);            // all 64 lanes execute
      float v = fmaxf(qn_s + macc[rg * 4 + e], 0.0f);
      if (col == 0) atomicMin(&dst[r], __float_as_uint(v));
    }
  }
}

// ---------------- Kernel B: sqrt + mean + exact top-k mean per row,
// then atomicAdd into out (out zeroed by pack_kernel) -----------------------
__global__ __launch_bounds__(BT) void select_kernel(
    const unsigned* __restrict__ minsq, float* __restrict__ out) {
  const int row = blockIdx.x;                // 0..15 = b*2+dir
  const unsigned* src = minsq + (size_t)row * NPTS;
  const int tid = threadIdx.x;

  __shared__ float sf[4];
  __shared__ int   si[4];

  const int PER = NPTS / BT;  // 16 values per thread
  float d[PER];
  float sum_all = 0.0f;
#pragma unroll
  for (int j = 0; j < PER; j++) {
    float v = sqrtf(__uint_as_float(src[tid + BT * j]));
    d[j] = v;
    sum_all += v;
  }

  // block float sum of sum_all
  {
    float v = sum_all;
    for (int off = 32; off > 0; off >>= 1) v += __shfl_down(v, off);
    if ((tid & 63) == 0) sf[tid >> 6] = v;
    __syncthreads();
    sum_all = sf[0] + sf[1] + sf[2] + sf[3];
    __syncthreads();
  }

  // radix-select the TOPK-th largest value (exact, over float bit patterns)
  unsigned sel = 0u;
  for (int bit = 30; bit >= 0; --bit) {   // sign bit is 0 (nonneg)
    unsigned cand = sel | (1u << bit);
    int c = 0;
#pragma unroll
    for (int j = 0; j < PER; j++) c += (__float_as_uint(d[j]) >= cand) ? 1 : 0;
    for (int off = 32; off > 0; off >>= 1) c += __shfl_down(c, off);
    if ((tid & 63) == 0) si[tid >> 6] = c;
    __syncthreads();
    int total = si[0] + si[1] + si[2] + si[3];
    __syncthreads();
    if (total >= TOPK) sel = cand;
  }

  // sum of strictly-greater values + count
  int cgt = 0;
  float sgt = 0.0f;
#pragma unroll
  for (int j = 0; j < PER; j++) {
    if (__float_as_uint(d[j]) > sel) { cgt++; sgt += d[j]; }
  }
  {
    float v = sgt;
    for (int off = 32; off > 0; off >>= 1) v += __shfl_down(v, off);
    if ((tid & 63) == 0) sf[tid >> 6] = v;
    int c = cgt;
    for (int off = 32; off > 0; off >>= 1) c += __shfl_down(c, off);
    if ((tid & 63) == 0) si[tid >> 6] = c;
    __syncthreads();
    sgt = sf[0] + sf[1] + sf[2] + sf[3];
    cgt = si[0] + si[1] + si[2] + si[3];
  }

  if (tid == 0) {
    float kth = __uint_as_float(sel);
    float topk_sum = sgt + (float)(TOPK - cgt) * kth;  // tie-exact vs lax.top_k
    float rowval = sum_all / (float)NPTS + 3.0f * (topk_sum / (float)TOPK);
    atomicAdd(out, rowval * (1.0f / (float)BATCH));
  }
}

extern "C" void kernel_launch(void* const* d_in, const int* in_sizes, int n_in,
                              void* d_out, int out_size, void* d_ws, size_t ws_size,
                              hipStream_t stream) {
  const float* pred = (const float*)d_in[0];
  const float* gt   = (const float*)d_in[1];
  float* out = (float*)d_out;

  unsigned* minsq = (unsigned*)d_ws;                       // [16][4096] = 256 KB
  uint2*    gpack = (uint2*)((char*)d_ws + (size_t)NROW * NPTS * 4);  // 512 KB

  pack_kernel<<<NROW, BT, 0, stream>>>(pred, gt, gpack, minsq, out);
  dim3 gridA(NPTS / 128, GSPLIT, NROW);  // (32,2,16) = 1024 blocks
  nn_min_kernel<<<gridA, BT, 0, stream>>>(pred, gt, gpack, minsq);
  select_kernel<<<NROW, BT, 0, stream>>>(minsq, out);
}